// Round 1
// baseline (1824.039 us; speedup 1.0000x reference)
//
#include <hip/hip_runtime.h>
#include <hip/hip_bf16.h>

#define DIM   384
#define NWIN  49
#define HEADS 12
#define NWMSK 64

typedef unsigned short ushort;
using bf16x8 = __attribute__((ext_vector_type(8))) short;
using f32x4  = __attribute__((ext_vector_type(4))) float;

__device__ __forceinline__ ushort f2bf(float f) {
  unsigned u = __float_as_uint(f);
  u += 0x7fff + ((u >> 16) & 1);          // RNE
  return (ushort)(u >> 16);
}

typedef __attribute__((address_space(1))) const void gas_void;
typedef __attribute__((address_space(3))) void las_void;

__device__ __forceinline__ void gload16(const ushort* g, ushort* l) {
  __builtin_amdgcn_global_load_lds((gas_void*)g, (las_void*)l, 16, 0, 0);
}

__global__ void prep_kernel(const float* __restrict__ qkv_w, const float* __restrict__ proj_w,
                            const float* __restrict__ bias_table, const int* __restrict__ rel_index,
                            ushort* __restrict__ wqb, ushort* __restrict__ wpb,
                            float* __restrict__ bias12) {
  int i0 = blockIdx.x * 256 + threadIdx.x;
  int stride = gridDim.x * 256;
  for (int i = i0; i < 1152 * 384; i += stride) wqb[i] = f2bf(qkv_w[i]);
  for (int i = i0; i < 384 * 384;  i += stride) wpb[i] = f2bf(proj_w[i]);
  for (int i = i0; i < HEADS * NWIN * NWIN; i += stride) {
    int h = i / (NWIN * NWIN);
    int rem = i - h * (NWIN * NWIN);
    bias12[i] = bias_table[rel_index[rem] * HEADS + h];
  }
}

// LDS layout (ushort elements)
#define XS_OFF 0        // [64][392]  x window bf16 (rows>=49 zero)
#define WB_OFF 25088    // [2][96][64] weight chunk double buffer (xor-swizzled content)
#define QS_OFF 37376    // [64][40]   q (scaled) bf16
#define KS_OFF 39936    // [64][40]   k bf16
#define VT_OFF 42496    // [32][72]   v transposed bf16
#define PS_OFF 44800    // [64][72]   P bf16
#define AO_OFF 49408    // [64][392]  attn out bf16
#define SMEM_USHORTS 74496   // 148992 bytes

__global__ __launch_bounds__(256, 1) void winattn_kernel(
    const float* __restrict__ x, const float* __restrict__ mask,
    const float* __restrict__ qkv_b, const float* __restrict__ proj_b,
    const ushort* __restrict__ wqb, const ushort* __restrict__ wpb,
    const float* __restrict__ bias12, float* __restrict__ out)
{
  extern __shared__ ushort smem[];
  ushort* xs = smem + XS_OFF;
  ushort* wb = smem + WB_OFF;
  ushort* qs = smem + QS_OFF;
  ushort* ks = smem + KS_OFF;
  ushort* vt = smem + VT_OFF;
  ushort* ps = smem + PS_OFF;
  ushort* ao = smem + AO_OFF;

  const int b   = blockIdx.x;
  const int tid = threadIdx.x;
  const int w = tid >> 6;       // wave 0..3
  const int l = tid & 63;
  const int c = l & 15;
  const int g = l >> 4;
  const int mh = w & 1;         // M-half (2 tiles of 16)
  const int nh = w >> 1;        // N-half (3 tiles of 16)
  const int wdx = b & (NWMSK - 1);
  const float scale = 0.17677669529663687f;  // 32^-0.5
  const float LOG2E = 1.4426950408889634f;

  // ---- stage x window -> bf16 LDS [64][392], pad rows zeroed
  {
    const float* xb = x + (size_t)b * (NWIN * DIM);
    #pragma unroll
    for (int it = 0; it < 12; ++it) {
      int j = tid + it * 256;         // 3072 chunks of 8 elems
      int row = j / 48;
      int c8  = j - row * 48;
      float4 f0 = make_float4(0.f, 0.f, 0.f, 0.f), f1 = f0;
      if (row < NWIN) {
        const float4* s4 = (const float4*)(xb + row * DIM + c8 * 8);
        f0 = s4[0]; f1 = s4[1];
      }
      ushort tmp[8] = { f2bf(f0.x), f2bf(f0.y), f2bf(f0.z), f2bf(f0.w),
                        f2bf(f1.x), f2bf(f1.y), f2bf(f1.z), f2bf(f1.w) };
      *(bf16x8*)&xs[row * 392 + c8 * 8] = *(bf16x8*)tmp;
    }
  }

  // stage one [96][64] bf16 weight chunk into wb half `buf`.
  // LDS is linear [96][64]; the SOURCE address carries the xor-swizzle so the
  // ds_read side (n*64 + ((k16 ^ (n&7))<<3)) is bank-conflict-free.
  auto stage_w = [&](const ushort* wsrc, int sel, int isqkv, int kc, int buf) {
    #pragma unroll
    for (int s = 0; s < 3; ++s) {
      int i = (w * 3 + s) * 64 + l;   // 0..767 : n = i>>3, c16 = i&7
      int n = i >> 3;
      int c16 = i & 7;
      int grow;
      if (isqkv) {                    // rows: q(0-31), k(32-63), v(64-95) of head sel
        int which = n >> 5;
        int d = n & 31;
        grow = which * 384 + sel * 32 + d;
      } else {                        // proj rows nb*96 + n
        grow = sel * 96 + n;
      }
      const ushort* src = wsrc + (size_t)grow * DIM + kc * 64 + ((c16 ^ (n & 7)) << 3);
      ushort* dst = wb + buf * 6144 + (w * 3 + s) * 512;   // wave-uniform base
      gload16(src, dst);
    }
  };

  __syncthreads();

  // ================= per-head: QKV GEMM + attention =================
  for (int h = 0; h < HEADS; ++h) {
    f32x4 acc[2][3] = {};
    stage_w(wqb, h, 1, 0, 0);
    for (int kc = 0; kc < 6; ++kc) {
      __syncthreads();                       // chunk kc staged; prev compute done
      if (kc < 5) stage_w(wqb, h, 1, kc + 1, (kc + 1) & 1);
      const ushort* wcb = wb + (kc & 1) * 6144;
      #pragma unroll
      for (int kk = 0; kk < 2; ++kk) {
        bf16x8 a0 = *(const bf16x8*)&xs[(mh * 32 + c)      * 392 + kc * 64 + kk * 32 + g * 8];
        bf16x8 a1 = *(const bf16x8*)&xs[(mh * 32 + 16 + c) * 392 + kc * 64 + kk * 32 + g * 8];
        int swz = ((kk * 4 + g) ^ (c & 7)) << 3;
        #pragma unroll
        for (int nt = 0; nt < 3; ++nt) {
          int n = (nh * 3 + nt) * 16 + c;
          bf16x8 bb = *(const bf16x8*)&wcb[n * 64 + swz];
          acc[0][nt] = __builtin_amdgcn_mfma_f32_16x16x32_bf16(a0, bb, acc[0][nt], 0, 0, 0);
          acc[1][nt] = __builtin_amdgcn_mfma_f32_16x16x32_bf16(a1, bb, acc[1][nt], 0, 0, 0);
        }
      }
    }
    // epilogue: scatter q (scaled), k, v^T into LDS
    #pragma unroll
    for (int mt = 0; mt < 2; ++mt) {
      #pragma unroll
      for (int nt = 0; nt < 3; ++nt) {
        int gnt = nh * 3 + nt;               // global n-tile 0..5
        int which = gnt >> 1;
        int d = (gnt & 1) * 16 + c;
        float qb_ = qkv_b[which * 384 + h * 32 + d];
        #pragma unroll
        for (int r = 0; r < 4; ++r) {
          int tok = (mh * 2 + mt) * 16 + g * 4 + r;
          float v = acc[mt][nt][r] + qb_;
          if (which == 0)      qs[tok * 40 + d] = f2bf(v * scale);
          else if (which == 1) ks[tok * 40 + d] = f2bf(v);
          else                 vt[d * 72 + tok] = f2bf(v);
        }
      }
    }
    __syncthreads();

    // S = (q*scale) k^T : wave w owns M-tile w (16 q rows)
    f32x4 sacc[4] = {};
    {
      bf16x8 aq = *(const bf16x8*)&qs[(w * 16 + c) * 40 + g * 8];
      #pragma unroll
      for (int kt = 0; kt < 4; ++kt) {
        bf16x8 bk = *(const bf16x8*)&ks[(kt * 16 + c) * 40 + g * 8];
        sacc[kt] = __builtin_amdgcn_mfma_f32_16x16x32_bf16(aq, bk, sacc[kt], 0, 0, 0);
      }
    }
    // bias + mask + key masking
    float s_[4][4];
    #pragma unroll
    for (int kt = 0; kt < 4; ++kt) {
      int key = kt * 16 + c;
      #pragma unroll
      for (int r = 0; r < 4; ++r) {
        int q = w * 16 + g * 4 + r;
        float sv = sacc[kt][r];
        if (key >= NWIN) sv = -3.0e38f;
        else if (q < NWIN)
          sv += bias12[(h * NWIN + q) * NWIN + key] + mask[(wdx * NWIN + q) * NWIN + key];
        s_[kt][r] = sv;
      }
    }
    // wave-parallel softmax: row q = w*16 + g*4 + r lives in 16 lanes (c) x 4 regs (kt)
    #pragma unroll
    for (int r = 0; r < 4; ++r) {
      float mx = fmaxf(fmaxf(s_[0][r], s_[1][r]), fmaxf(s_[2][r], s_[3][r]));
      mx = fmaxf(mx, __shfl_xor(mx, 1, 64));
      mx = fmaxf(mx, __shfl_xor(mx, 2, 64));
      mx = fmaxf(mx, __shfl_xor(mx, 4, 64));
      mx = fmaxf(mx, __shfl_xor(mx, 8, 64));
      float p0 = __builtin_exp2f((s_[0][r] - mx) * LOG2E);
      float p1 = __builtin_exp2f((s_[1][r] - mx) * LOG2E);
      float p2 = __builtin_exp2f((s_[2][r] - mx) * LOG2E);
      float p3 = __builtin_exp2f((s_[3][r] - mx) * LOG2E);
      float sum = p0 + p1 + p2 + p3;
      sum += __shfl_xor(sum, 1, 64);
      sum += __shfl_xor(sum, 2, 64);
      sum += __shfl_xor(sum, 4, 64);
      sum += __shfl_xor(sum, 8, 64);
      float inv = 1.0f / sum;
      int q = w * 16 + g * 4 + r;
      ps[q * 72 +  0 + c] = f2bf(p0 * inv);
      ps[q * 72 + 16 + c] = f2bf(p1 * inv);
      ps[q * 72 + 32 + c] = f2bf(p2 * inv);
      ps[q * 72 + 48 + c] = f2bf(p3 * inv);
    }
    // PV: out_tile = P @ v   (A = P rows of M-tile w, B = v^T)
    f32x4 pacc[2] = {};
    #pragma unroll
    for (int kk = 0; kk < 2; ++kk) {
      bf16x8 ap = *(const bf16x8*)&ps[(w * 16 + c) * 72 + kk * 32 + g * 8];
      #pragma unroll
      for (int dt = 0; dt < 2; ++dt) {
        bf16x8 bv = *(const bf16x8*)&vt[(dt * 16 + c) * 72 + kk * 32 + g * 8];
        pacc[dt] = __builtin_amdgcn_mfma_f32_16x16x32_bf16(ap, bv, pacc[dt], 0, 0, 0);
      }
    }
    #pragma unroll
    for (int dt = 0; dt < 2; ++dt)
      #pragma unroll
      for (int r = 0; r < 4; ++r) {
        int tok = w * 16 + g * 4 + r;
        ao[tok * 392 + h * 32 + dt * 16 + c] = f2bf(pacc[dt][r]);
      }
  }

  // ================= proj GEMM: out = ao @ proj_w^T + proj_b =================
  __syncthreads();
  for (int nb = 0; nb < 4; ++nb) {
    f32x4 acc[2][3] = {};
    stage_w(wpb, nb, 0, 0, 0);
    for (int kc = 0; kc < 6; ++kc) {
      __syncthreads();
      if (kc < 5) stage_w(wpb, nb, 0, kc + 1, (kc + 1) & 1);
      const ushort* wcb = wb + (kc & 1) * 6144;
      #pragma unroll
      for (int kk = 0; kk < 2; ++kk) {
        bf16x8 a0 = *(const bf16x8*)&ao[(mh * 32 + c)      * 392 + kc * 64 + kk * 32 + g * 8];
        bf16x8 a1 = *(const bf16x8*)&ao[(mh * 32 + 16 + c) * 392 + kc * 64 + kk * 32 + g * 8];
        int swz = ((kk * 4 + g) ^ (c & 7)) << 3;
        #pragma unroll
        for (int nt = 0; nt < 3; ++nt) {
          int n = (nh * 3 + nt) * 16 + c;
          bf16x8 bb = *(const bf16x8*)&wcb[n * 64 + swz];
          acc[0][nt] = __builtin_amdgcn_mfma_f32_16x16x32_bf16(a0, bb, acc[0][nt], 0, 0, 0);
          acc[1][nt] = __builtin_amdgcn_mfma_f32_16x16x32_bf16(a1, bb, acc[1][nt], 0, 0, 0);
        }
      }
    }
    #pragma unroll
    for (int mt = 0; mt < 2; ++mt) {
      #pragma unroll
      for (int nt = 0; nt < 3; ++nt) {
        int col = nb * 96 + (nh * 3 + nt) * 16 + c;
        float pb = proj_b[col];
        #pragma unroll
        for (int r = 0; r < 4; ++r) {
          int tok = (mh * 2 + mt) * 16 + g * 4 + r;
          if (tok < NWIN)
            out[((size_t)b * NWIN + tok) * DIM + col] = acc[mt][nt][r] + pb;
        }
      }
    }
  }
}

extern "C" void kernel_launch(void* const* d_in, const int* in_sizes, int n_in,
                              void* d_out, int out_size, void* d_ws, size_t ws_size,
                              hipStream_t stream) {
  const float* x          = (const float*)d_in[0];
  const float* mask       = (const float*)d_in[1];
  const float* bias_table = (const float*)d_in[2];
  const float* qkv_w      = (const float*)d_in[3];
  const float* qkv_b      = (const float*)d_in[4];
  const float* proj_w     = (const float*)d_in[5];
  const float* proj_b     = (const float*)d_in[6];
  const int*   rel_index  = (const int*)d_in[7];
  float* out = (float*)d_out;

  // ws layout: wqb bf16 [1152*384] @0 ; wpb bf16 [384*384] @884736 ; bias12 f32 [12*49*49] @1179648
  ushort* wqb   = (ushort*)d_ws;
  ushort* wpb   = (ushort*)((char*)d_ws + 884736);
  float*  bias12= (float*)((char*)d_ws + 1179648);

  hipFuncSetAttribute((const void*)winattn_kernel,
                      hipFuncAttributeMaxDynamicSharedMemorySize, 149504);

  prep_kernel<<<256, 256, 0, stream>>>(qkv_w, proj_w, bias_table, rel_index, wqb, wpb, bias12);
  winattn_kernel<<<4096, 256, SMEM_USHORTS * 2, stream>>>(
      x, mask, qkv_b, proj_b, wqb, wpb, bias12, out);
}

// Round 2
// 1017.935 us; speedup vs baseline: 1.7919x; 1.7919x over previous
//
#include <hip/hip_runtime.h>
#include <hip/hip_bf16.h>

#define DIM   384
#define NWIN  49
#define HEADS 12

typedef unsigned short ushort;
using bf16x8 = __attribute__((ext_vector_type(8))) short;
using u16x4  = __attribute__((ext_vector_type(4))) ushort;
using f32x4  = __attribute__((ext_vector_type(4))) float;

__device__ __forceinline__ ushort f2bf(float f) {
  unsigned u = __float_as_uint(f);
  u += 0x7fff + ((u >> 16) & 1);          // RNE
  return (ushort)(u >> 16);
}

typedef __attribute__((address_space(1))) const void gas_void;
typedef __attribute__((address_space(3))) void las_void;

__device__ __forceinline__ void gload16(const ushort* g, ushort* l) {
  __builtin_amdgcn_global_load_lds((gas_void*)g, (las_void*)l, 16, 0, 0);
}

// prep: bf16 weights + combined (bias[rel_index] + mask) table bm[64][12][49][49]
__global__ void prep_kernel(const float* __restrict__ qkv_w, const float* __restrict__ proj_w,
                            const float* __restrict__ bias_table, const int* __restrict__ rel_index,
                            const float* __restrict__ mask,
                            ushort* __restrict__ wqb, ushort* __restrict__ wpb,
                            float* __restrict__ bm) {
  int i0 = blockIdx.x * 256 + threadIdx.x;
  int stride = gridDim.x * 256;
  for (int i = i0; i < 1152 * 384; i += stride) wqb[i] = f2bf(qkv_w[i]);
  for (int i = i0; i < 384 * 384;  i += stride) wpb[i] = f2bf(proj_w[i]);
  for (int i = i0; i < 64 * HEADS * NWIN * NWIN; i += stride) {
    int wdx = i / (HEADS * NWIN * NWIN);
    int rem = i - wdx * (HEADS * NWIN * NWIN);
    int h = rem / (NWIN * NWIN);
    int qk = rem - h * (NWIN * NWIN);
    bm[i] = bias_table[rel_index[qk] * HEADS + h] + mask[wdx * (NWIN * NWIN) + qk];
  }
}

// LDS layout (ushort offsets)
#define XS 0        // [128][384] x (later: attn-out), XOR-swizzled granules
#define WB 49152    // 2 x [96][64] weight chunk dbuf (swizzled content)
#define QS 61440    // 2 win x [64][40]
#define KS 66560    // 2 win x [64][40]
#define VT 71680    // 2 win x [32][72]
#define PS 76288    // 2 win x [64][40]  (wave-private rows)
#define SMEM_USHORTS 81408   // 162816 bytes

__global__ __launch_bounds__(512, 2) void winattn_kernel(
    const float* __restrict__ x, const float* __restrict__ qkv_b,
    const float* __restrict__ proj_b, const ushort* __restrict__ wqb,
    const ushort* __restrict__ wpb, const float* __restrict__ bm,
    float* __restrict__ out)
{
  extern __shared__ ushort smem[];
  ushort* xs = smem + XS;
  ushort* wb = smem + WB;

  const int blk = blockIdx.x;
  const int tid = threadIdx.x;
  const int w = tid >> 6, l = tid & 63;
  const int c = l & 15, g = l >> 4;
  const int wm = w >> 1, wn = w & 1;      // GEMM wave grid: 4M x 2N
  const int win = w >> 2, wq = w & 3;     // attn wave grid: 2 windows x 4 q-tiles
  const float scale = 0.17677669529663687f;   // 32^-0.5
  const float LOG2E = 1.4426950408889634f;

  ushort* qsw = smem + QS + win * 2560;
  ushort* ksw = smem + KS + win * 2560;
  ushort* vtw = smem + VT + win * 2304;
  ushort* psw = smem + PS + win * 2560;

  // stage one [96][64] weight chunk into wb half `buf` (linear LDS dest,
  // xor-swizzle carried on the global SOURCE address)
  auto stage_w = [&](const ushort* wsrc, int sel, int isqkv, int kc, int buf) {
    #pragma unroll
    for (int s = 0; s < 2; ++s) {
      int i = s * 512 + tid;              // 0..1023, need < 768 (wave-uniform cut)
      if (i < 768) {
        int n = i >> 3, c16 = i & 7;
        int grow = isqkv ? ((n >> 5) * 384 + sel * 32 + (n & 31)) : (sel * 96 + n);
        const ushort* src = wsrc + (size_t)grow * DIM + kc * 64 + ((c16 ^ (n & 7)) << 3);
        gload16(src, wb + buf * 6144 + i * 8);
      }
    }
  };

  // GEMM chunk: A = xs rows (swizzled), B = wb chunk; acc[2][3] per wave
  auto compute_chunk = [&](int kc, int buf, f32x4 (&acc)[2][3]) {
    const ushort* wcb = wb + buf * 6144;
    #pragma unroll
    for (int kk = 0; kk < 2; ++kk) {
      int row0 = wm * 32 + c;
      int sA = ((kc * 8 + kk * 4 + g) ^ (c & 7)) << 3;
      bf16x8 a0 = *(const bf16x8*)&xs[row0 * 384 + sA];
      bf16x8 a1 = *(const bf16x8*)&xs[(row0 + 16) * 384 + sA];
      int sB = ((kk * 4 + g) ^ (c & 7)) << 3;
      #pragma unroll
      for (int nt = 0; nt < 3; ++nt) {
        int n = (wn * 3 + nt) * 16 + c;
        bf16x8 bb = *(const bf16x8*)&wcb[n * 64 + sB];
        acc[0][nt] = __builtin_amdgcn_mfma_f32_16x16x32_bf16(a0, bb, acc[0][nt], 0, 0, 0);
        acc[1][nt] = __builtin_amdgcn_mfma_f32_16x16x32_bf16(a1, bb, acc[1][nt], 0, 0, 0);
      }
    }
  };

  // prefetch first weight chunk, then stage x (2 windows) -> swizzled bf16 LDS
  stage_w(wqb, 0, 1, 0, 0);
  {
    const float* xb = x + (size_t)blk * (2 * NWIN * DIM);
    for (int i = tid; i < 9408; i += 512) {        // 9408 float4 = 2*49*384 floats
      float4 f = ((const float4*)xb)[i];
      int idx = i * 4;
      int wi = idx / 18816;
      int rem = idx - wi * 18816;
      int tok = rem / 384;
      int k = rem - tok * 384;
      int row = wi * 64 + tok;
      int gr = (k >> 3) ^ (tok & 7);
      u16x4 v4 = { f2bf(f.x), f2bf(f.y), f2bf(f.z), f2bf(f.w) };
      *(u16x4*)&xs[row * 384 + (gr << 3) + (k & 7)] = v4;
    }
    bf16x8 z8 = {};
    for (int t = tid; t < 1440; t += 512) {        // zero pad rows 49..63, both windows
      int j = t * 8;
      int wi = j / 5760;
      int rem = j - wi * 5760;
      int tok = 49 + rem / 384;
      int k = rem - (rem / 384) * 384;
      *(bf16x8*)&xs[((wi * 64 + tok)) * 384 + k] = z8;
    }
  }

  unsigned aop[48];   // packed bf16 attn-out stash: [h][dt][rpair] (static idx via unroll)

  // ================= per-head: QKV GEMM (M=128) + attention =================
  #pragma unroll
  for (int h = 0; h < HEADS; ++h) {
    f32x4 acc[2][3] = {};
    for (int kc = 0; kc < 6; ++kc) {
      __syncthreads();                     // prev compute done; staged chunk landed (vmcnt auto)
      if (kc < 5)       stage_w(wqb, h, 1, kc + 1, (kc + 1) & 1);
      else if (h < 11)  stage_w(wqb, h + 1, 1, 0, 0);
      else              stage_w(wpb, 0, 0, 0, 0);   // prefetch proj nb0 kc0
      compute_chunk(kc, kc & 1, acc);
    }
    // epilogue: scatter q (scaled), k, v^T into this head's LDS buffers
    {
      int winE = wm >> 1;
      ushort* qsE = smem + QS + winE * 2560;
      ushort* ksE = smem + KS + winE * 2560;
      ushort* vtE = smem + VT + winE * 2304;
      #pragma unroll
      for (int mt = 0; mt < 2; ++mt) {
        #pragma unroll
        for (int nt = 0; nt < 3; ++nt) {
          int gnt = wn * 3 + nt;
          int which = gnt >> 1;
          int d = (gnt & 1) * 16 + c;
          float qb_ = qkv_b[which * 384 + h * 32 + d];
          #pragma unroll
          for (int r = 0; r < 4; ++r) {
            int tok = (wm & 1) * 32 + mt * 16 + g * 4 + r;
            float v = acc[mt][nt][r] + qb_;
            if (which == 0)      qsE[tok * 40 + d] = f2bf(v * scale);
            else if (which == 1) ksE[tok * 40 + d] = f2bf(v);
            else                 vtE[d * 72 + tok] = f2bf(v);
          }
        }
      }
    }
    __syncthreads();

    // ---- attention: wave handles (win, q-tile wq)
    f32x4 sacc[4] = {};
    {
      bf16x8 aq = *(const bf16x8*)&qsw[(wq * 16 + c) * 40 + g * 8];
      #pragma unroll
      for (int kt = 0; kt < 4; ++kt) {
        bf16x8 bk = *(const bf16x8*)&ksw[(kt * 16 + c) * 40 + g * 8];
        sacc[kt] = __builtin_amdgcn_mfma_f32_16x16x32_bf16(aq, bk, sacc[kt], 0, 0, 0);
      }
    }
    const int wdx = ((blk << 1) + win) & 63;
    const float* bmh = bm + (size_t)(wdx * HEADS + h) * (NWIN * NWIN);
    float s_[4][4];
    #pragma unroll
    for (int kt = 0; kt < 4; ++kt) {
      int key = kt * 16 + c;
      #pragma unroll
      for (int r = 0; r < 4; ++r) {
        int q = wq * 16 + g * 4 + r;
        float sv = sacc[kt][r];
        if (key >= NWIN) sv = -3.0e38f;
        else if (q < NWIN) sv += bmh[q * NWIN + key];
        s_[kt][r] = sv;
      }
    }
    float p[4][4];
    #pragma unroll
    for (int r = 0; r < 4; ++r) {
      float mx = fmaxf(fmaxf(s_[0][r], s_[1][r]), fmaxf(s_[2][r], s_[3][r]));
      mx = fmaxf(mx, __shfl_xor(mx, 1, 64));
      mx = fmaxf(mx, __shfl_xor(mx, 2, 64));
      mx = fmaxf(mx, __shfl_xor(mx, 4, 64));
      mx = fmaxf(mx, __shfl_xor(mx, 8, 64));
      float p0 = __builtin_exp2f((s_[0][r] - mx) * LOG2E);
      float p1 = __builtin_exp2f((s_[1][r] - mx) * LOG2E);
      float p2 = __builtin_exp2f((s_[2][r] - mx) * LOG2E);
      float p3 = __builtin_exp2f((s_[3][r] - mx) * LOG2E);
      float sum = p0 + p1 + p2 + p3;
      sum += __shfl_xor(sum, 1, 64);
      sum += __shfl_xor(sum, 2, 64);
      sum += __shfl_xor(sum, 4, 64);
      sum += __shfl_xor(sum, 8, 64);
      float inv = 1.0f / sum;
      p[0][r] = p0 * inv; p[1][r] = p1 * inv; p[2][r] = p2 * inv; p[3][r] = p3 * inv;
    }
    // PV in two 32-key chunks through wave-private ps rows
    f32x4 pacc2[2] = {};
    #pragma unroll
    for (int kkh = 0; kkh < 2; ++kkh) {
      #pragma unroll
      for (int t = 0; t < 2; ++t) {
        int kt = kkh * 2 + t;
        #pragma unroll
        for (int r = 0; r < 4; ++r)
          psw[(wq * 16 + g * 4 + r) * 40 + t * 16 + c] = f2bf(p[kt][r]);
      }
      bf16x8 ap = *(const bf16x8*)&psw[(wq * 16 + c) * 40 + g * 8];
      #pragma unroll
      for (int dt = 0; dt < 2; ++dt) {
        bf16x8 bv = *(const bf16x8*)&vtw[(dt * 16 + c) * 72 + kkh * 32 + g * 8];
        pacc2[dt] = __builtin_amdgcn_mfma_f32_16x16x32_bf16(ap, bv, pacc2[dt], 0, 0, 0);
      }
    }
    // stash attn-out in registers (packed bf16 pairs over row-pairs)
    #pragma unroll
    for (int dt = 0; dt < 2; ++dt)
      #pragma unroll
      for (int rp = 0; rp < 2; ++rp)
        aop[h * 4 + dt * 2 + rp] = (unsigned)f2bf(pacc2[dt][2 * rp]) |
                                   ((unsigned)f2bf(pacc2[dt][2 * rp + 1]) << 16);
  }

  // spill stash into xs region (x is dead) as swizzled bf16 [128][384]
  #pragma unroll
  for (int h2 = 0; h2 < HEADS; ++h2) {
    #pragma unroll
    for (int dt = 0; dt < 2; ++dt) {
      #pragma unroll
      for (int rp = 0; rp < 2; ++rp) {
        unsigned u = aop[h2 * 4 + dt * 2 + rp];
        int gr = h2 * 4 + dt * 2 + (c >> 3);
        int tok0 = wq * 16 + g * 4 + rp * 2;
        int row0 = win * 64 + tok0;
        int row1 = row0 + 1;
        xs[row0 * 384 + (((gr ^ (row0 & 7)) << 3) | (c & 7))] = (ushort)(u & 0xffff);
        xs[row1 * 384 + (((gr ^ (row1 & 7)) << 3) | (c & 7))] = (ushort)(u >> 16);
      }
    }
  }

  // ================= fused proj GEMM: out = ao @ proj_w^T + proj_b =================
  for (int nb = 0; nb < 4; ++nb) {
    f32x4 acc[2][3] = {};
    for (int kc = 0; kc < 6; ++kc) {
      __syncthreads();
      if (kc < 5)      stage_w(wpb, nb, 0, kc + 1, (kc + 1) & 1);
      else if (nb < 3) stage_w(wpb, nb + 1, 0, 0, 0);
      compute_chunk(kc, kc & 1, acc);
    }
    #pragma unroll
    for (int mt = 0; mt < 2; ++mt) {
      #pragma unroll
      for (int nt = 0; nt < 3; ++nt) {
        int col = nb * 96 + (wn * 3 + nt) * 16 + c;
        float pb = proj_b[col];
        #pragma unroll
        for (int r = 0; r < 4; ++r) {
          int mrow = wm * 32 + mt * 16 + g * 4 + r;
          int tok = mrow & 63;
          if (tok < NWIN)
            out[((size_t)((blk << 1) + (mrow >> 6)) * NWIN + tok) * DIM + col] =
                acc[mt][nt][r] + pb;
        }
      }
    }
  }
}

extern "C" void kernel_launch(void* const* d_in, const int* in_sizes, int n_in,
                              void* d_out, int out_size, void* d_ws, size_t ws_size,
                              hipStream_t stream) {
  const float* x          = (const float*)d_in[0];
  const float* mask       = (const float*)d_in[1];
  const float* bias_table = (const float*)d_in[2];
  const float* qkv_w      = (const float*)d_in[3];
  const float* qkv_b      = (const float*)d_in[4];
  const float* proj_w     = (const float*)d_in[5];
  const float* proj_b     = (const float*)d_in[6];
  const int*   rel_index  = (const int*)d_in[7];
  float* out = (float*)d_out;

  // ws: wqb bf16 @0 (884736 B); wpb bf16 @884736 (294912 B); bm f32 @1179648 (7375872 B)
  ushort* wqb = (ushort*)d_ws;
  ushort* wpb = (ushort*)((char*)d_ws + 884736);
  float*  bm  = (float*)((char*)d_ws + 1179648);

  hipFuncSetAttribute((const void*)winattn_kernel,
                      hipFuncAttributeMaxDynamicSharedMemorySize, SMEM_USHORTS * 2);

  prep_kernel<<<256, 256, 0, stream>>>(qkv_w, proj_w, bias_table, rel_index, mask, wqb, wpb, bm);
  winattn_kernel<<<2048, 512, SMEM_USHORTS * 2, stream>>>(
      x, qkv_b, proj_b, wqb, wpb, bm, out);
}